// Round 12
// baseline (748.952 us; speedup 1.0000x reference)
//
#include <hip/hip_runtime.h>
#include <hip/hip_bf16.h>
#include <hip/hip_fp16.h>
#include <math.h>
#include <float.h>

#define BB 16
#define TT 1023
#define CC 2048
#define M_ROWS (BB * TT)   // 16368
#define MP 16384           // padded rows
#define N3 (3 * CC)        // 6144
#define NCH 16             // scan chunks
#define CHL 64             // chunk length

typedef __attribute__((ext_vector_type(8))) short bfrag;   // 8 bf16 (4 VGPRs)
typedef __attribute__((ext_vector_type(4))) float f32x4;   // MFMA C/D frag
typedef __attribute__((ext_vector_type(4))) short short4v;

__device__ __forceinline__ void async16(const void* g, void* l) {
  __builtin_amdgcn_global_load_lds((const __attribute__((address_space(1))) void*)g,
                                   (__attribute__((address_space(3))) void*)l, 16, 0, 0);
}

__device__ __forceinline__ short bfb(float f) {
  __hip_bfloat16 h = __float2bfloat16(f);
  return *reinterpret_cast<short*>(&h);
}

// ---------------- merged prep: build_xm (blocks 0..MP) + weight cast ----------------
__global__ void prep(const float* __restrict__ x, const float* __restrict__ xx,
                     const float* __restrict__ tmix,
                     const float* __restrict__ Wk, const float* __restrict__ Wv,
                     const float* __restrict__ Wr, const float* __restrict__ Wo,
                     __hip_bfloat16* __restrict__ xm,
                     __hip_bfloat16* __restrict__ W3, __hip_bfloat16* __restrict__ WoB) {
  int bid = blockIdx.x;
  if (bid < MP) {
    int m = bid;
    short* orow = (short*)xm + (size_t)m * CC;
    if (m >= M_ROWS) {
      for (int c = threadIdx.x; c < CC / 4; c += 256)
        ((short4v*)orow)[c] = short4v{0, 0, 0, 0};
      return;
    }
    int b = m / TT, t = m - b * TT;
    const float* xrow = x + (size_t)m * CC;
    const float* xprev = (t == 0) ? (xx + (size_t)b * CC) : (xrow - CC);
    for (int c = threadIdx.x; c < CC / 4; c += 256) {
      float4 xv = ((const float4*)xrow)[c];
      float4 pv = ((const float4*)xprev)[c];
      float4 tm = ((const float4*)tmix)[c];
      ((short4v*)orow)[c] = short4v{
          bfb(xv.x * tm.x + pv.x * (1.0f - tm.x)),
          bfb(xv.y * tm.y + pv.y * (1.0f - tm.y)),
          bfb(xv.z * tm.z + pv.z * (1.0f - tm.z)),
          bfb(xv.w * tm.w + pv.w * (1.0f - tm.w))};
    }
  } else {
    size_t i4 = (size_t)(bid - MP) * 256 + threadIdx.x;   // covers CC*CC/4
    size_t i = i4 * 4;
    float4 a = *(const float4*)(Wk + i);
    float4 b = *(const float4*)(Wv + i);
    float4 c = *(const float4*)(Wr + i);
    float4 d = *(const float4*)(Wo + i);
    *(short4v*)((short*)W3 + i)               = short4v{bfb(a.x), bfb(a.y), bfb(a.z), bfb(a.w)};
    *(short4v*)((short*)W3 + i + CC * CC)     = short4v{bfb(b.x), bfb(b.y), bfb(b.z), bfb(b.w)};
    *(short4v*)((short*)W3 + i + 2 * CC * CC) = short4v{bfb(c.x), bfb(c.y), bfb(c.z), bfb(c.w)};
    *(short4v*)((short*)WoB + i)              = short4v{bfb(d.x), bfb(d.y), bfb(d.z), bfb(d.w)};
  }
}

// ---------------- 256x256-tile 8-phase bf16 MFMA GEMM, 16x16x32 frags ----------------
// C[m,n] = sum_k A[m,k]*B[n,k].  8 waves (2M x 4N), BK=64 as 2 K-halves.
// LDS: 2 buf x 2 khalf x {A,B} regions of 256x32 bf16 (16 KB each) = 128 KB.
// Swizzle: 16B chunk at (row, slot) holds kgrp = slot ^ ((row>>1)&3) (0-conflict).
// Schedule = r11 measured-best: ONE barrier per phase
//   { ds_read frags(p); stage s_p; MFMA(p); [VM(4) on ph4/ph8]; barrier }
// r12 change: XCD chunking is m-major (consecutive swz share n) so each
// chunk's 1 MB B-panel stays XCD-L2-resident and A panels get L3-served;
// prior n-major walk re-streamed the full 25 MB B per m-group (FETCH 730MB).
// MODE1 epilogue now also folds sigmoid into the r-third store.
template <int MODE>
__global__ __launch_bounds__(512, 2)
void gemm256(const short* __restrict__ A, const short* __restrict__ Bw,
             float* __restrict__ outF, __half* __restrict__ outH,
             __hip_bfloat16* __restrict__ outV, __hip_bfloat16* __restrict__ outR) {
  __shared__ short lds[65536];   // 128 KiB

  const int lane = threadIdx.x & 63, wid = threadIdx.x >> 6;
  const int wr = wid >> 2, wc = wid & 3;

  // XCD-aware swizzle, m-major within chunk (grids are multiples of 8)
  const int nx = gridDim.x, ny = gridDim.y;
  const int nwg = nx * ny;
  const int bid = blockIdx.y * nx + blockIdx.x;
  const int q = nwg >> 3;
  const int swz = (bid & 7) * q + (bid >> 3);
  const int mBase = (swz % ny) * 256;     // m cycles fast -> B-panel stays hot
  const int nBase = (swz / ny) * 256;

  // staging: wave wid covers rows [wid*32, wid*32+32) of the 256-row region
  const int srow = lane >> 2;                                  // 0..15
  const int scol = (((lane & 3) ^ ((lane >> 3) & 3)) * 8);     // inverse-swizzled k-group
  const int stgOff = wid * 1024 + lane * 8;                    // shorts
  const short* aSrcBase = A  + (size_t)(mBase + wid * 32 + srow) * CC + scol;
  const short* bSrcBase = Bw + (size_t)(nBase + wid * 32 + srow) * CC + scol;

  // ds_read: frag lane -> (row = R0 + (l&15), kgrp = l>>4), swizzled slot
  const int ldOff = (lane & 15) * 32 + (((lane >> 4) ^ ((lane >> 1) & 3)) * 8);  // shorts

  f32x4 acc[2][4][4] = {};
  bfrag bq[4];

#define RGNA(buf, kh) ((buf) * 32768 + (kh) * 8192)
#define RGNB(buf, kh) (16384 + (buf) * 32768 + (kh) * 8192)

#define STG_A(buf, kh, tk) do { \
    const short* _s = aSrcBase + ((tk) * 64 + (kh) * 32); \
    short* _d = lds + RGNA(buf, kh) + stgOff; \
    async16(_s, _d); async16(_s + (size_t)16 * CC, _d + 512); } while (0)

#define STG_B(buf, kh, tk) do { \
    const short* _s = bSrcBase + ((tk) * 64 + (kh) * 32); \
    short* _d = lds + RGNB(buf, kh) + stgOff; \
    async16(_s, _d); async16(_s + (size_t)16 * CC, _d + 512); } while (0)

#define VMN(n) asm volatile("s_waitcnt vmcnt(" #n ")" ::: "memory")

// phase: reads ; stage ; MFMA ; wait ; ONE barrier
#define PH(buf, kh, mh, STAGE, WAIT) do { \
    bfrag aq[4]; \
    if ((mh) == 0) { \
      _Pragma("unroll") \
      for (int n = 0; n < 4; ++n) \
        bq[n] = *(const bfrag*)(lds + RGNB(buf, kh) + (wc * 64 + n * 16) * 32 + ldOff); \
    } \
    _Pragma("unroll") \
    for (int f = 0; f < 4; ++f) \
      aq[f] = *(const bfrag*)(lds + RGNA(buf, kh) + (wr * 128 + (mh) * 64 + f * 16) * 32 + ldOff); \
    STAGE; \
    __builtin_amdgcn_s_setprio(1); \
    _Pragma("unroll") \
    for (int f = 0; f < 4; ++f) \
      _Pragma("unroll") \
      for (int n = 0; n < 4; ++n) \
        acc[mh][f][n] = __builtin_amdgcn_mfma_f32_16x16x32_bf16(aq[f], bq[n], acc[mh][f][n], 0, 0, 0); \
    __builtin_amdgcn_s_setprio(0); \
    WAIT; \
    __builtin_amdgcn_s_barrier(); } while (0)

  // prologue: tile0 -> buf0 (4 units), tile1.K0 -> buf1 (2 units).
  // VM(4): units 1..4 (all of buf0) landed; u5,u6 may fly.
  STG_A(0, 0, 0); STG_B(0, 0, 0);
  STG_A(0, 1, 0); STG_B(0, 1, 0);
  STG_A(1, 0, 1); STG_B(1, 0, 1);
  VMN(4);
  __builtin_amdgcn_s_barrier();

  // steady state: s1..s8 = A11,B11,A00,B00,A01,B01,A10,B10 (next tiles).
  // ph4-VM(4): retires {prev s7,s8, s1,s2} -> covers ph5..8 reads (buf1).
  // ph8-VM(4): retires {s3..s6} -> covers next iter ph1..4 reads (buf0).
  for (int ti = 0; ti < 30; ti += 2) {
    PH(0, 0, 0, STG_A(1, 1, ti + 1), );
    PH(0, 0, 1, STG_B(1, 1, ti + 1), );
    PH(0, 1, 0, STG_A(0, 0, ti + 2), );
    PH(0, 1, 1, STG_B(0, 0, ti + 2), VMN(4));
    PH(1, 0, 0, STG_A(0, 1, ti + 2), );
    PH(1, 0, 1, STG_B(0, 1, ti + 2), );
    PH(1, 1, 0, STG_A(1, 0, ti + 3), );
    PH(1, 1, 1, STG_B(1, 0, ti + 3), VMN(4));
  }
  // epilogue: tile 30 in buf0 (staged), tile 31 in buf1 (K0 staged; K1 here).
  PH(0, 0, 0, STG_A(1, 1, 31), );
  PH(0, 0, 1, STG_B(1, 1, 31), );
  PH(0, 1, 0, , );
  PH(0, 1, 1, , VMN(4));
  PH(1, 0, 0, , );
  PH(1, 0, 1, , VMN(0));
  PH(1, 1, 0, , );
  PH(1, 1, 1, , );

#undef PH
#undef VMN
#undef STG_A
#undef STG_B
#undef RGNA
#undef RGNB

  // C-write: col = lane&15, row = (lane>>4)*4 + rr (verified layout)
  // MODE 1: k -> exp(k) fp16; v -> bf16; r -> sigmoid(r) bf16 (fused epilogue).
#pragma unroll
  for (int mh = 0; mh < 2; ++mh)
#pragma unroll
    for (int f = 0; f < 4; ++f) {
      const int row0 = mBase + wr * 128 + mh * 64 + f * 16 + (lane >> 4) * 4;
      const int col0 = nBase + wc * 64 + (lane & 15);
#pragma unroll
      for (int n = 0; n < 4; ++n) {
        const int col = col0 + n * 16;
#pragma unroll
        for (int rr = 0; rr < 4; ++rr) {
          const int row = row0 + rr;
          if (row < M_ROWS) {
            float val = acc[mh][f][n][rr];
            if constexpr (MODE == 0) {
              outF[(size_t)row * CC + col] = val;
            } else {
              if (col < CC)          outH[(size_t)row * CC + col] = __float2half(expf(val));
              else if (col < 2 * CC) outV[(size_t)row * CC + (col - CC)] = __float2bfloat16(val);
              else                   outR[(size_t)row * CC + (col - 2 * CC)] =
                                         __float2bfloat16(1.0f / (1.0f + expf(-val)));
            }
          }
        }
      }
    }
}

// ---------------- chunked parallel scan + sig*wkv/wk ----------------
// ek = exp(k) fp16 and sig = sigmoid(r) bf16 precomputed by GEMM1 epilogue.
// Renorm-free (ratio invariant); state init bb*exp(mm), aa*exp(mm).
__global__ __launch_bounds__(1024)
void scan_fuse2(const __half* __restrict__ ek, const __hip_bfloat16* __restrict__ v,
                const __hip_bfloat16* __restrict__ sg, const float* __restrict__ aa,
                const float* __restrict__ bb, const float* __restrict__ mm,
                const float* __restrict__ tdec, const float* __restrict__ tfir,
                __hip_bfloat16* __restrict__ rwkv) {
  __shared__ float sBk[NCH][64], sBkv[NCH][64], sSk[NCH][64], sSkv[NCH][64];

  const int lane = threadIdx.x & 63, wid = threadIdx.x >> 6;
  const int c = blockIdx.x * 64 + lane;
  const int b = blockIdx.y;
  const int i = b * CC + c;

  const float dexp = expf(tdec[c]);
  const float d    = expf(-dexp);
  const float ef   = expf(tfir[c]);

  const int t0 = wid * CHL;
  const int t1 = (t0 + CHL < TT) ? t0 + CHL : TT;
  const size_t base = (size_t)b * TT * CC + c;

  if (wid < NCH - 1) {
    float Bk = 0.0f, Bkv = 0.0f;
    size_t off = base + (size_t)t0 * CC;
#pragma unroll 4
    for (int t = t0; t < t1; ++t, off += CC) {
      float kk = __half2float(ek[off]);
      float kv = kk * __bfloat162float(v[off]);
      Bk = d * Bk + kk;
      Bkv = d * Bkv + kv;
    }
    sBk[wid][lane] = Bk;
    sBkv[wid][lane] = Bkv;
  }
  __syncthreads();

  if (wid == 0) {
    const float d64 = expf(-dexp * (float)CHL);
    const float sc = expf(mm[i]);
    float S = bb[i] * sc, Sv = aa[i] * sc;
#pragma unroll
    for (int j = 0; j < NCH; ++j) {
      sSk[j][lane] = S;
      sSkv[j][lane] = Sv;
      if (j < NCH - 1) {
        S = d64 * S + sBk[j][lane];
        Sv = d64 * Sv + sBkv[j][lane];
      }
    }
  }
  __syncthreads();

  float S = sSk[wid][lane], Sv = sSkv[wid][lane];
  size_t off = base + (size_t)t0 * CC;
#pragma unroll 4
  for (int t = t0; t < t1; ++t, off += CC) {
    float kk = __half2float(ek[off]);
    float vv = __bfloat162float(v[off]);
    float sig = __bfloat162float(sg[off]);
    float kv = kk * vv;
    float wk = ef * kk + S;
    float wkv = ef * kv + Sv;
    S = d * S + kk;
    Sv = d * Sv + kv;
    float ratio = wkv / wk;
    if (isnan(ratio)) ratio = 0.0f;
    else if (isinf(ratio)) ratio = ratio > 0.0f ? FLT_MAX : -FLT_MAX;
    rwkv[off] = __float2bfloat16(sig * ratio);
  }
}

extern "C" void kernel_launch(void* const* d_in, const int* in_sizes, int n_in,
                              void* d_out, int out_size, void* d_ws, size_t ws_size,
                              hipStream_t stream) {
  const float* x    = (const float*)d_in[0];
  const float* tdec = (const float*)d_in[1];
  const float* tfir = (const float*)d_in[2];
  const float* tmix = (const float*)d_in[3];
  const float* Wk   = (const float*)d_in[4];
  const float* Wv   = (const float*)d_in[5];
  const float* Wr   = (const float*)d_in[6];
  const float* Wo   = (const float*)d_in[7];
  const float* xx   = (const float*)d_in[8];
  const float* aa   = (const float*)d_in[9];
  const float* bb   = (const float*)d_in[10];
  const float* mm   = (const float*)d_in[11];

  char* ws = (char*)d_ws;
  size_t o = 0;
  __hip_bfloat16* W3  = (__hip_bfloat16*)(ws + o); o += (size_t)N3 * CC * 2;
  __hip_bfloat16* WoB = (__hip_bfloat16*)(ws + o); o += (size_t)CC * CC * 2;
  __hip_bfloat16* xmB = (__hip_bfloat16*)(ws + o); o += (size_t)MP * CC * 2;
  __hip_bfloat16* vB  = (__hip_bfloat16*)(ws + o); o += (size_t)MP * CC * 2;
  __hip_bfloat16* sgB = (__hip_bfloat16*)(ws + o); o += (size_t)MP * CC * 2;

  __half* ekH = (__half*)d_out;        // exp(k) fp16 lives in d_out until GEMM2
  __hip_bfloat16* rwkvB = xmB;         // rwkv reuses xm buffer (xm dead after GEMM1)

  prep<<<MP + CC * CC / 1024, 256, 0, stream>>>(x, xx, tmix, Wk, Wv, Wr, Wo,
                                                xmB, W3, WoB);
  gemm256<1><<<dim3(N3 / 256, MP / 256), 512, 0, stream>>>(
      (const short*)xmB, (const short*)W3, nullptr, ekH, vB, sgB);
  scan_fuse2<<<dim3(CC / 64, BB), 1024, 0, stream>>>(ekH, vB, sgB, aa, bb, mm,
                                                     tdec, tfir, rwkvB);
  gemm256<0><<<dim3(CC / 256, MP / 256), 512, 0, stream>>>(
      (const short*)rwkvB, (const short*)WoB, (float*)d_out, nullptr, nullptr, nullptr);
}

// Round 13
// 703.664 us; speedup vs baseline: 1.0644x; 1.0644x over previous
//
#include <hip/hip_runtime.h>
#include <hip/hip_bf16.h>
#include <hip/hip_fp16.h>
#include <math.h>
#include <float.h>

#define BB 16
#define TT 1023
#define CC 2048
#define M_ROWS (BB * TT)   // 16368
#define MP 16384           // padded rows
#define N3 (3 * CC)        // 6144
#define NCH 16             // scan chunks
#define CHL 64             // chunk length

typedef __attribute__((ext_vector_type(8))) short bfrag;   // 8 bf16 (4 VGPRs)
typedef __attribute__((ext_vector_type(4))) float f32x4;   // MFMA C/D frag
typedef __attribute__((ext_vector_type(4))) short short4v;

__device__ __forceinline__ void async16(const void* g, void* l) {
  __builtin_amdgcn_global_load_lds((const __attribute__((address_space(1))) void*)g,
                                   (__attribute__((address_space(3))) void*)l, 16, 0, 0);
}

__device__ __forceinline__ short bfb(float f) {
  __hip_bfloat16 h = __float2bfloat16(f);
  return *reinterpret_cast<short*>(&h);
}

// ---------------- merged prep: build_xm (blocks 0..MP) + weight cast ----------------
__global__ void prep(const float* __restrict__ x, const float* __restrict__ xx,
                     const float* __restrict__ tmix,
                     const float* __restrict__ Wk, const float* __restrict__ Wv,
                     const float* __restrict__ Wr, const float* __restrict__ Wo,
                     __hip_bfloat16* __restrict__ xm,
                     __hip_bfloat16* __restrict__ W3, __hip_bfloat16* __restrict__ WoB) {
  int bid = blockIdx.x;
  if (bid < MP) {
    int m = bid;
    short* orow = (short*)xm + (size_t)m * CC;
    if (m >= M_ROWS) {
      for (int c = threadIdx.x; c < CC / 4; c += 256)
        ((short4v*)orow)[c] = short4v{0, 0, 0, 0};
      return;
    }
    int b = m / TT, t = m - b * TT;
    const float* xrow = x + (size_t)m * CC;
    const float* xprev = (t == 0) ? (xx + (size_t)b * CC) : (xrow - CC);
    for (int c = threadIdx.x; c < CC / 4; c += 256) {
      float4 xv = ((const float4*)xrow)[c];
      float4 pv = ((const float4*)xprev)[c];
      float4 tm = ((const float4*)tmix)[c];
      ((short4v*)orow)[c] = short4v{
          bfb(xv.x * tm.x + pv.x * (1.0f - tm.x)),
          bfb(xv.y * tm.y + pv.y * (1.0f - tm.y)),
          bfb(xv.z * tm.z + pv.z * (1.0f - tm.z)),
          bfb(xv.w * tm.w + pv.w * (1.0f - tm.w))};
    }
  } else {
    size_t i4 = (size_t)(bid - MP) * 256 + threadIdx.x;   // covers CC*CC/4
    size_t i = i4 * 4;
    float4 a = *(const float4*)(Wk + i);
    float4 b = *(const float4*)(Wv + i);
    float4 c = *(const float4*)(Wr + i);
    float4 d = *(const float4*)(Wo + i);
    *(short4v*)((short*)W3 + i)               = short4v{bfb(a.x), bfb(a.y), bfb(a.z), bfb(a.w)};
    *(short4v*)((short*)W3 + i + CC * CC)     = short4v{bfb(b.x), bfb(b.y), bfb(b.z), bfb(b.w)};
    *(short4v*)((short*)W3 + i + 2 * CC * CC) = short4v{bfb(c.x), bfb(c.y), bfb(c.z), bfb(c.w)};
    *(short4v*)((short*)WoB + i)              = short4v{bfb(d.x), bfb(d.y), bfb(d.z), bfb(d.w)};
  }
}

// ---------------- 256x256-tile 8-phase bf16 MFMA GEMM, 16x16x32 frags ----------------
// C[m,n] = sum_k A[m,k]*B[n,k].  8 waves (2M x 4N), BK=64 as 2 K-halves.
// LDS: 2 buf x 2 khalf x {A,B} regions of 256x32 bf16 (16 KB each) = 128 KB.
// Swizzle: 16B chunk at (row, slot) holds kgrp = slot ^ ((row>>1)&3) (0-conflict).
// Schedule = r11 measured-best: ONE barrier per phase
//   { ds_read frags(p); stage s_p; MFMA(p); [VM(4) on ph4/ph8]; barrier }
// XCD swizzle: n-major within chunk (r11 direction, measured best) — keeps the
// 1 MB A-panel XCD-L2-resident while streaming L3-cached B.  (The r12 m-major
// flip re-streamed 67MB A per n-col: FETCH 730->811MB, MfmaUtil -9pts. Reverted.)
// MODE1 epilogue: k -> exp(k) fp16, r -> sigmoid(r) bf16 (fused).
template <int MODE>
__global__ __launch_bounds__(512, 2)
void gemm256(const short* __restrict__ A, const short* __restrict__ Bw,
             float* __restrict__ outF, __half* __restrict__ outH,
             __hip_bfloat16* __restrict__ outV, __hip_bfloat16* __restrict__ outR) {
  __shared__ short lds[65536];   // 128 KiB

  const int lane = threadIdx.x & 63, wid = threadIdx.x >> 6;
  const int wr = wid >> 2, wc = wid & 3;

  // XCD-aware swizzle, n-major within chunk (grids are multiples of 8)
  const int nx = gridDim.x;
  const int nwg = nx * gridDim.y;
  const int bid = blockIdx.y * nx + blockIdx.x;
  const int q = nwg >> 3;
  const int swz = (bid & 7) * q + (bid >> 3);
  const int mBase = (swz / nx) * 256;
  const int nBase = (swz % nx) * 256;

  // staging: wave wid covers rows [wid*32, wid*32+32) of the 256-row region
  const int srow = lane >> 2;                                  // 0..15
  const int scol = (((lane & 3) ^ ((lane >> 3) & 3)) * 8);     // inverse-swizzled k-group
  const int stgOff = wid * 1024 + lane * 8;                    // shorts
  const short* aSrcBase = A  + (size_t)(mBase + wid * 32 + srow) * CC + scol;
  const short* bSrcBase = Bw + (size_t)(nBase + wid * 32 + srow) * CC + scol;

  // ds_read: frag lane -> (row = R0 + (l&15), kgrp = l>>4), swizzled slot
  const int ldOff = (lane & 15) * 32 + (((lane >> 4) ^ ((lane >> 1) & 3)) * 8);  // shorts

  f32x4 acc[2][4][4] = {};
  bfrag bq[4];

#define RGNA(buf, kh) ((buf) * 32768 + (kh) * 8192)
#define RGNB(buf, kh) (16384 + (buf) * 32768 + (kh) * 8192)

#define STG_A(buf, kh, tk) do { \
    const short* _s = aSrcBase + ((tk) * 64 + (kh) * 32); \
    short* _d = lds + RGNA(buf, kh) + stgOff; \
    async16(_s, _d); async16(_s + (size_t)16 * CC, _d + 512); } while (0)

#define STG_B(buf, kh, tk) do { \
    const short* _s = bSrcBase + ((tk) * 64 + (kh) * 32); \
    short* _d = lds + RGNB(buf, kh) + stgOff; \
    async16(_s, _d); async16(_s + (size_t)16 * CC, _d + 512); } while (0)

#define VMN(n) asm volatile("s_waitcnt vmcnt(" #n ")" ::: "memory")

// phase: reads ; stage ; MFMA ; wait ; ONE barrier
#define PH(buf, kh, mh, STAGE, WAIT) do { \
    bfrag aq[4]; \
    if ((mh) == 0) { \
      _Pragma("unroll") \
      for (int n = 0; n < 4; ++n) \
        bq[n] = *(const bfrag*)(lds + RGNB(buf, kh) + (wc * 64 + n * 16) * 32 + ldOff); \
    } \
    _Pragma("unroll") \
    for (int f = 0; f < 4; ++f) \
      aq[f] = *(const bfrag*)(lds + RGNA(buf, kh) + (wr * 128 + (mh) * 64 + f * 16) * 32 + ldOff); \
    STAGE; \
    __builtin_amdgcn_s_setprio(1); \
    _Pragma("unroll") \
    for (int f = 0; f < 4; ++f) \
      _Pragma("unroll") \
      for (int n = 0; n < 4; ++n) \
        acc[mh][f][n] = __builtin_amdgcn_mfma_f32_16x16x32_bf16(aq[f], bq[n], acc[mh][f][n], 0, 0, 0); \
    __builtin_amdgcn_s_setprio(0); \
    WAIT; \
    __builtin_amdgcn_s_barrier(); } while (0)

  // prologue: tile0 -> buf0 (4 units), tile1.K0 -> buf1 (2 units).
  // VM(4): units 1..4 (all of buf0) landed; u5,u6 may fly.
  STG_A(0, 0, 0); STG_B(0, 0, 0);
  STG_A(0, 1, 0); STG_B(0, 1, 0);
  STG_A(1, 0, 1); STG_B(1, 0, 1);
  VMN(4);
  __builtin_amdgcn_s_barrier();

  // steady state: s1..s8 = A11,B11,A00,B00,A01,B01,A10,B10 (next tiles).
  // ph4-VM(4): retires {prev s7,s8, s1,s2} -> covers ph5..8 reads (buf1).
  // ph8-VM(4): retires {s3..s6} -> covers next iter ph1..4 reads (buf0).
  for (int ti = 0; ti < 30; ti += 2) {
    PH(0, 0, 0, STG_A(1, 1, ti + 1), );
    PH(0, 0, 1, STG_B(1, 1, ti + 1), );
    PH(0, 1, 0, STG_A(0, 0, ti + 2), );
    PH(0, 1, 1, STG_B(0, 0, ti + 2), VMN(4));
    PH(1, 0, 0, STG_A(0, 1, ti + 2), );
    PH(1, 0, 1, STG_B(0, 1, ti + 2), );
    PH(1, 1, 0, STG_A(1, 0, ti + 3), );
    PH(1, 1, 1, STG_B(1, 0, ti + 3), VMN(4));
  }
  // epilogue: tile 30 in buf0 (staged), tile 31 in buf1 (K0 staged; K1 here).
  PH(0, 0, 0, STG_A(1, 1, 31), );
  PH(0, 0, 1, STG_B(1, 1, 31), );
  PH(0, 1, 0, , );
  PH(0, 1, 1, , VMN(4));
  PH(1, 0, 0, , );
  PH(1, 0, 1, , VMN(0));
  PH(1, 1, 0, , );
  PH(1, 1, 1, , );

#undef PH
#undef VMN
#undef STG_A
#undef STG_B
#undef RGNA
#undef RGNB

  // C-write: col = lane&15, row = (lane>>4)*4 + rr (verified layout)
  // MODE 1: k -> exp(k) fp16; v -> bf16; r -> sigmoid(r) bf16 (fused epilogue).
#pragma unroll
  for (int mh = 0; mh < 2; ++mh)
#pragma unroll
    for (int f = 0; f < 4; ++f) {
      const int row0 = mBase + wr * 128 + mh * 64 + f * 16 + (lane >> 4) * 4;
      const int col0 = nBase + wc * 64 + (lane & 15);
#pragma unroll
      for (int n = 0; n < 4; ++n) {
        const int col = col0 + n * 16;
#pragma unroll
        for (int rr = 0; rr < 4; ++rr) {
          const int row = row0 + rr;
          if (row < M_ROWS) {
            float val = acc[mh][f][n][rr];
            if constexpr (MODE == 0) {
              outF[(size_t)row * CC + col] = val;
            } else {
              if (col < CC)          outH[(size_t)row * CC + col] = __float2half(expf(val));
              else if (col < 2 * CC) outV[(size_t)row * CC + (col - CC)] = __float2bfloat16(val);
              else                   outR[(size_t)row * CC + (col - 2 * CC)] =
                                         __float2bfloat16(1.0f / (1.0f + expf(-val)));
            }
          }
        }
      }
    }
}

// ---------------- chunked parallel scan + sig*wkv/wk ----------------
// ek = exp(k) fp16 and sig = sigmoid(r) bf16 precomputed by GEMM1 epilogue.
// Renorm-free (ratio invariant); state init bb*exp(mm), aa*exp(mm).
__global__ __launch_bounds__(1024)
void scan_fuse2(const __half* __restrict__ ek, const __hip_bfloat16* __restrict__ v,
                const __hip_bfloat16* __restrict__ sg, const float* __restrict__ aa,
                const float* __restrict__ bb, const float* __restrict__ mm,
                const float* __restrict__ tdec, const float* __restrict__ tfir,
                __hip_bfloat16* __restrict__ rwkv) {
  __shared__ float sBk[NCH][64], sBkv[NCH][64], sSk[NCH][64], sSkv[NCH][64];

  const int lane = threadIdx.x & 63, wid = threadIdx.x >> 6;
  const int c = blockIdx.x * 64 + lane;
  const int b = blockIdx.y;
  const int i = b * CC + c;

  const float dexp = expf(tdec[c]);
  const float d    = expf(-dexp);
  const float ef   = expf(tfir[c]);

  const int t0 = wid * CHL;
  const int t1 = (t0 + CHL < TT) ? t0 + CHL : TT;
  const size_t base = (size_t)b * TT * CC + c;

  if (wid < NCH - 1) {
    float Bk = 0.0f, Bkv = 0.0f;
    size_t off = base + (size_t)t0 * CC;
#pragma unroll 4
    for (int t = t0; t < t1; ++t, off += CC) {
      float kk = __half2float(ek[off]);
      float kv = kk * __bfloat162float(v[off]);
      Bk = d * Bk + kk;
      Bkv = d * Bkv + kv;
    }
    sBk[wid][lane] = Bk;
    sBkv[wid][lane] = Bkv;
  }
  __syncthreads();

  if (wid == 0) {
    const float d64 = expf(-dexp * (float)CHL);
    const float sc = expf(mm[i]);
    float S = bb[i] * sc, Sv = aa[i] * sc;
#pragma unroll
    for (int j = 0; j < NCH; ++j) {
      sSk[j][lane] = S;
      sSkv[j][lane] = Sv;
      if (j < NCH - 1) {
        S = d64 * S + sBk[j][lane];
        Sv = d64 * Sv + sBkv[j][lane];
      }
    }
  }
  __syncthreads();

  float S = sSk[wid][lane], Sv = sSkv[wid][lane];
  size_t off = base + (size_t)t0 * CC;
#pragma unroll 4
  for (int t = t0; t < t1; ++t, off += CC) {
    float kk = __half2float(ek[off]);
    float vv = __bfloat162float(v[off]);
    float sig = __bfloat162float(sg[off]);
    float kv = kk * vv;
    float wk = ef * kk + S;
    float wkv = ef * kv + Sv;
    S = d * S + kk;
    Sv = d * Sv + kv;
    float ratio = wkv / wk;
    if (isnan(ratio)) ratio = 0.0f;
    else if (isinf(ratio)) ratio = ratio > 0.0f ? FLT_MAX : -FLT_MAX;
    rwkv[off] = __float2bfloat16(sig * ratio);
  }
}

extern "C" void kernel_launch(void* const* d_in, const int* in_sizes, int n_in,
                              void* d_out, int out_size, void* d_ws, size_t ws_size,
                              hipStream_t stream) {
  const float* x    = (const float*)d_in[0];
  const float* tdec = (const float*)d_in[1];
  const float* tfir = (const float*)d_in[2];
  const float* tmix = (const float*)d_in[3];
  const float* Wk   = (const float*)d_in[4];
  const float* Wv   = (const float*)d_in[5];
  const float* Wr   = (const float*)d_in[6];
  const float* Wo   = (const float*)d_in[7];
  const float* xx   = (const float*)d_in[8];
  const float* aa   = (const float*)d_in[9];
  const float* bb   = (const float*)d_in[10];
  const float* mm   = (const float*)d_in[11];

  char* ws = (char*)d_ws;
  size_t o = 0;
  __hip_bfloat16* W3  = (__hip_bfloat16*)(ws + o); o += (size_t)N3 * CC * 2;
  __hip_bfloat16* WoB = (__hip_bfloat16*)(ws + o); o += (size_t)CC * CC * 2;
  __hip_bfloat16* xmB = (__hip_bfloat16*)(ws + o); o += (size_t)MP * CC * 2;
  __hip_bfloat16* vB  = (__hip_bfloat16*)(ws + o); o += (size_t)MP * CC * 2;
  __hip_bfloat16* sgB = (__hip_bfloat16*)(ws + o); o += (size_t)MP * CC * 2;

  __half* ekH = (__half*)d_out;        // exp(k) fp16 lives in d_out until GEMM2
  __hip_bfloat16* rwkvB = xmB;         // rwkv reuses xm buffer (xm dead after GEMM1)

  prep<<<MP + CC * CC / 1024, 256, 0, stream>>>(x, xx, tmix, Wk, Wv, Wr, Wo,
                                                xmB, W3, WoB);
  gemm256<1><<<dim3(N3 / 256, MP / 256), 512, 0, stream>>>(
      (const short*)xmB, (const short*)W3, nullptr, ekH, vB, sgB);
  scan_fuse2<<<dim3(CC / 64, BB), 1024, 0, stream>>>(ekH, vB, sgB, aa, bb, mm,
                                                     tdec, tfir, rwkvB);
  gemm256<0><<<dim3(CC / 256, MP / 256), 512, 0, stream>>>(
      (const short*)rwkvB, (const short*)WoB, (float*)d_out, nullptr, nullptr, nullptr);
}